// Round 1
// baseline (410.023 us; speedup 1.0000x reference)
//
#include <hip/hip_runtime.h>
#include <stdint.h>

// Problem: T=1024, B=32, C=1024, K=1024, E=16
//   out0 (T,B,C) fp32 = x + einsum('rboi,tbi->tbo', (resp@pw_w1).reshape(1,B,C,C), x)
//   out1 scalar loss
//
// R3 changes vs R2:
//   - gemm: 256x256 macro-tile, 512 threads (8 waves, 2Mx4N, wave tile 128x64),
//     BK=32 with a 4-deep LDS ring (128 KB) and COUNTED vmcnt(12) gates.
//     Loads for tile t+3 are issued at iter t and stay in flight across
//     barriers (never vmcnt(0) in the main loop) -> removes the per-K-iter
//     staging drain that capped R2 at ~577 TF (2-phase structure ceiling).
//     Two 16-MFMA sub-phases per tile with mid-barrier + s_setprio(1).
//     LDS swizzle upgraded to (r&3)^((r>>2)&3) (plain r&3 is 4-way at 64B rows).
//   - prep: convert stage grid-strided (2048 blocks x 16 float4) instead of
//     32768 single-float4 blocks.

#define TBC   (1024*32*1024)   // 33554432

typedef __attribute__((ext_vector_type(8))) __bf16 bf16x8;
typedef __attribute__((ext_vector_type(4))) float  floatx4;

#define XSWZ(r) ((((r) & 3) ^ (((r) >> 2) & 3)))

__device__ __forceinline__ unsigned short f2bf(float f) {
  unsigned u = __float_as_uint(f);
  unsigned r = u + 0x7fffu + ((u >> 16) & 1u);   // RNE
  return (unsigned short)(r >> 16);
}
__device__ __forceinline__ float bf2f(unsigned short u) {
  return __uint_as_float(((unsigned)u) << 16);
}

// global -> LDS async DMA, 16 B per lane; LDS dest is wave-uniform base,
// HW scatters lane i to base + i*16.
__device__ __forceinline__ void async16(const void* g, void* l) {
  __builtin_amdgcn_global_load_lds(
      (const __attribute__((address_space(1))) void*)(unsigned long long)(uintptr_t)g,
      (__attribute__((address_space(3))) void*)(unsigned int)(uintptr_t)l,
      16, 0, 0);
}

// ---------------- stage 1: routing (one block per batch element) ----------
__global__ __launch_bounds__(256) void routing_kernel(
    const float* __restrict__ key, const float* __restrict__ aw,
    const float* __restrict__ ab, float* __restrict__ resp) {
  __shared__ float part[16][17];
  __shared__ float logit[16];
  const int b = blockIdx.x;
  const int tid = threadIdx.x;
  const int e = tid & 15, ks = tid >> 4;          // 16 k-slices of 64
  const float* kb = key + b * 1024 + ks * 64;
  float acc = 0.f;
  #pragma unroll 8
  for (int k = 0; k < 64; ++k)
    acc = fmaf(kb[k], aw[(ks * 64 + k) * 16 + e], acc);
  part[e][ks] = acc;
  __syncthreads();
  if (tid < 16) {
    float s = ab[tid];
    #pragma unroll
    for (int j = 0; j < 16; ++j) s += part[tid][j];
    logit[tid] = s;
  }
  __syncthreads();
  if (tid < 16) {
    float m = logit[0];
    #pragma unroll
    for (int j = 1; j < 16; ++j) m = fmaxf(m, logit[j]);
    float s = 0.f;
    #pragma unroll
    for (int j = 0; j < 16; ++j) s += expf(logit[j] - m);
    resp[b * 16 + tid] = expf(logit[tid] - m) / s;
  }
}

// ---------------- stage 2: loss --------------------------------------------
__global__ void loss_kernel(const float* __restrict__ resp, float* __restrict__ loss_out) {
  __shared__ float imp[16];
  const int tid = threadIdx.x;
  if (tid < 16) {
    float s = 0.f;
    for (int bb = 0; bb < 32; ++bb) s += resp[bb * 16 + tid];
    imp[tid] = s;
  }
  __syncthreads();
  if (tid == 0) {
    float mu = 0.f;
    for (int j = 0; j < 16; ++j) mu += imp[j];
    mu *= (1.f / 16.f);
    float var = 0.f;
    for (int j = 0; j < 16; ++j) { float d = imp[j] - mu; var += d * d; }
    var *= (1.f / 15.f);                      // ddof=1
    loss_out[0] = 0.01f * sqrtf(var) / mu;
  }
}

// ---------------- stage 3: fused convert (x->bf16) + mix -------------------
// blocks [0, 2048): grid-stride convert of 8388608 float4s of x -> xb
// blocks [2048, 3072): W[b] = sum_e resp[b,e]*pw_w1[e]  (bf16)
__global__ __launch_bounds__(256) void prep_kernel(
    const float4* __restrict__ x, ushort4* __restrict__ xb,
    const float4* __restrict__ pw, const float* __restrict__ resp,
    ushort4* __restrict__ W) {
  const int tid = threadIdx.x;
  if (blockIdx.x < 2048) {
    const int base = blockIdx.x * 256 + tid;     // 524288 threads
    #pragma unroll
    for (int j = 0; j < 16; ++j) {
      const int i = base + j * 524288;
      float4 v = x[i];
      ushort4 o;
      o.x = f2bf(v.x); o.y = f2bf(v.y); o.z = f2bf(v.z); o.w = f2bf(v.w);
      xb[i] = o;
    }
  } else {
    __shared__ float rs[512];
    rs[tid] = resp[tid];
    rs[tid + 256] = resp[tid + 256];
    __syncthreads();
    const int p = (blockIdx.x - 2048) * 256 + tid;   // 262144 vec4 positions
    float4 v[16];
    #pragma unroll
    for (int e = 0; e < 16; ++e) v[e] = pw[e * 262144 + p];
    #pragma unroll
    for (int b = 0; b < 32; ++b) {
      float ax = 0.f, ay = 0.f, az = 0.f, aww = 0.f;
      #pragma unroll
      for (int e = 0; e < 16; ++e) {
        const float r = rs[b * 16 + e];
        ax = fmaf(r, v[e].x, ax); ay = fmaf(r, v[e].y, ay);
        az = fmaf(r, v[e].z, az); aww = fmaf(r, v[e].w, aww);
      }
      ushort4 o;
      o.x = f2bf(ax); o.y = f2bf(ay); o.z = f2bf(az); o.w = f2bf(aww);
      W[(size_t)b * 262144 + p] = o;
    }
  }
}

// ---------------- stage 4: batched GEMM + residual -------------------------
// out[t,b,o] = bf2f(xb[t,b,o]) + sum_i xb[t,b,i] * W[b,o,i]
// 256x256 tile, 512 threads = 8 waves (2M x 4N), wave tile 128x64.
// BK=32, 4-buffer LDS ring (4 x (256x32 A + 256x32 B) bf16 = 128 KB).
// Deep pipeline: at iter t issue tile t+3's loads (dest freed by t-1's end
// barrier); gate with counted vmcnt(12) (tile t landed), never vmcnt(0)
// in steady state. Raw s_barrier (no compiler vmcnt(0) drain).
// Grid 512 blocks, 1 block/CU; batch pinned to XCD via gid&7.
__global__ __launch_bounds__(512, 2) void gemm_kernel(
    const unsigned short* __restrict__ xb,   // (T,B,C) bf16
    const unsigned short* __restrict__ Wb,   // (B,C,C) bf16 [b][o][i]
    float* __restrict__ out) {
  __shared__ unsigned short lds[4][2][8192];     // [buf][A/B][256 rows x 32 k]
  const int tid  = threadIdx.x;
  const int lane = tid & 63;
  const int wave = tid >> 6;                     // 0..7
  const int wm = wave >> 2;                      // 0..1 : 128-row half
  const int wn = wave & 3;                       // 0..3 : 64-col quarter

  const int gid   = blockIdx.x;                  // 0..511
  const int xcd   = gid & 7;
  const int local = gid >> 3;                    // 0..63
  const int b     = xcd * 4 + (local >> 4);      // 4 batches per XCD
  const int sub   = local & 15;
  const int t0    = (sub >> 2) * 256;
  const int o0    = (sub & 3) * 256;

  // staging source pointers: per tile each thread loads 2 A + 2 B chunks.
  // chunk s = j*512+tid -> row r = s>>2, slot c = s&3 holds global granule
  // c ^ XSWZ(r) (pre-swizzled source; linear LDS dest; read undoes the XOR).
  const unsigned short* gA[2];
  const unsigned short* gB[2];
  #pragma unroll
  for (int j = 0; j < 2; ++j) {
    const int s  = j * 512 + tid;
    const int r  = s >> 2;
    const int cg = (s & 3) ^ XSWZ(r);
    gA[j] = xb + (size_t)(t0 + r) * 32768 + (size_t)b * 1024 + cg * 8;
    gB[j] = Wb + (size_t)b * 1048576 + (size_t)(o0 + r) * 1024 + cg * 8;
  }

  floatx4 acc[8][4];
  #pragma unroll
  for (int a = 0; a < 8; ++a)
    #pragma unroll
    for (int ni = 0; ni < 4; ++ni)
      acc[a][ni] = floatx4{0.f, 0.f, 0.f, 0.f};

  auto stage = [&](int bufi) {
    #pragma unroll
    for (int j = 0; j < 2; ++j) {
      const int dst = (j * 512 + wave * 64) * 8;   // elems; lane adds +lane*8
      async16(gA[j], &lds[bufi][0][dst]);
      async16(gB[j], &lds[bufi][1][dst]);
      gA[j] += 32; gB[j] += 32;
    }
  };

  auto compute = [&](int bufi) {
    const unsigned short* lA = &lds[bufi][0][0];
    const unsigned short* lB = &lds[bufi][1][0];
    bf16x8 bfr[4];
    #pragma unroll
    for (int ni = 0; ni < 4; ++ni) {
      const int r = wn * 64 + ni * 16 + (lane & 15);
      const int slot = (lane >> 4) ^ XSWZ(r);
      bfr[ni] = *(const bf16x8*)(lB + r * 32 + slot * 8);
    }
    #pragma unroll
    for (int half = 0; half < 2; ++half) {
      bf16x8 afr[4];
      #pragma unroll
      for (int mi = 0; mi < 4; ++mi) {
        const int r = wm * 128 + half * 64 + mi * 16 + (lane & 15);
        const int slot = (lane >> 4) ^ XSWZ(r);
        afr[mi] = *(const bf16x8*)(lA + r * 32 + slot * 8);
      }
      __builtin_amdgcn_s_setprio(1);
      #pragma unroll
      for (int mi = 0; mi < 4; ++mi)
        #pragma unroll
        for (int ni = 0; ni < 4; ++ni)
          acc[half * 4 + mi][ni] = __builtin_amdgcn_mfma_f32_16x16x32_bf16(
              afr[mi], bfr[ni], acc[half * 4 + mi][ni], 0, 0, 0);
      __builtin_amdgcn_s_setprio(0);
      if (half == 0) __builtin_amdgcn_s_barrier();   // phase split (T5 fuel)
    }
  };

  // prologue: fill 3 of 4 ring slots (12 loads in flight / thread)
  stage(0); stage(1); stage(2);

  for (int t = 0; t < 32; ++t) {
    if (t <= 28) {
      stage((t + 3) & 3);        // dest buffer freed by iter t-1's end barrier
      asm volatile("s_waitcnt vmcnt(12)" ::: "memory");   // tile t landed
    } else if (t == 29) {
      asm volatile("s_waitcnt vmcnt(8)" ::: "memory");
    } else if (t == 30) {
      asm volatile("s_waitcnt vmcnt(4)" ::: "memory");
    } else {
      asm volatile("s_waitcnt vmcnt(0)" ::: "memory");
    }
    __builtin_amdgcn_s_barrier();          // tile t globally visible
    asm volatile("" ::: "memory");
    compute(t & 3);
    asm volatile("s_waitcnt lgkmcnt(0)" ::: "memory");  // my LDS reads done
    __builtin_amdgcn_s_barrier();          // buffer t&3 free for reuse
  }

  // epilogue: C/D layout col=lane&15, row=(lane>>4)*4+reg; residual from xb
  #pragma unroll
  for (int a = 0; a < 8; ++a) {
    const int tb = t0 + wm * 128 + (a >> 2) * 64 + (a & 3) * 16 + (lane >> 4) * 4;
    #pragma unroll
    for (int ni = 0; ni < 4; ++ni) {
      const int o = o0 + wn * 64 + ni * 16 + (lane & 15);
      #pragma unroll
      for (int v = 0; v < 4; ++v) {
        const size_t idx = (size_t)(tb + v) * 32768 + (size_t)b * 1024 + o;
        out[idx] = acc[a][ni][v] + bf2f(xb[idx]);
      }
    }
  }
}

extern "C" void kernel_launch(void* const* d_in, const int* in_sizes, int n_in,
                              void* d_out, int out_size, void* d_ws, size_t ws_size,
                              hipStream_t stream) {
  const float* x   = (const float*)d_in[0];   // (1024,32,1024)
  const float* key = (const float*)d_in[1];   // (1,32,1024)
  const float* aw  = (const float*)d_in[2];   // (1024,16)
  const float* ab  = (const float*)d_in[3];   // (16,)
  const float* pw  = (const float*)d_in[4];   // (16, 1048576)
  float* out = (float*)d_out;                 // 33554432 + 1

  char* ws = (char*)d_ws;
  unsigned short* Wb = (unsigned short*)ws;                    // 67108864 B
  unsigned short* xb = (unsigned short*)(ws + 67108864);       // 67108864 B
  float* resp        = (float*)(ws + 134217728);               // 2 KB

  routing_kernel<<<32, 256, 0, stream>>>(key, aw, ab, resp);
  loss_kernel<<<1, 64, 0, stream>>>(resp, out + TBC);
  prep_kernel<<<3072, 256, 0, stream>>>((const float4*)x, (ushort4*)xb,
                                        (const float4*)pw, resp, (ushort4*)Wb);
  gemm_kernel<<<512, 512, 0, stream>>>(xb, Wb, out);
}

// Round 2
// 402.930 us; speedup vs baseline: 1.0176x; 1.0176x over previous
//
#include <hip/hip_runtime.h>
#include <stdint.h>

// Problem: T=1024, B=32, C=1024, K=1024, E=16
//   out0 (T,B,C) fp32 = x + einsum('rboi,tbi->tbo', (resp@pw_w1).reshape(1,B,C,C), x)
//   out1 scalar loss
//
// R4 changes vs R3:
//   - prep_kernel split: its mix branch needed float4 v[16] = 64 VGPRs live,
//     but the co-compiled convert branch dragged the allocation to 48 ->
//     spill/remat of the pw tile every one of the 32 batch iterations
//     (~2 GB extra traffic; prep ran at 2 TB/s, 120 us). Now:
//       K1 route_conv : 32 routing blocks + 4096 convert blocks (independent)
//       K2 mix_loss   : 1024 mix blocks, __launch_bounds__(256,4) -> VGPR cap
//                       128, v[16] stays in registers; block 0 also computes
//                       the scalar loss from the LDS-staged resp.
//       K3 gemm       : UNCHANGED from R3 (get its counters next round).
//   - kernel count 4 -> 3 (inter-dispatch gap ~40 us each).

#define TBC   (1024*32*1024)   // 33554432

typedef __attribute__((ext_vector_type(8))) __bf16 bf16x8;
typedef __attribute__((ext_vector_type(4))) float  floatx4;

#define XSWZ(r) ((((r) & 3) ^ (((r) >> 2) & 3)))

__device__ __forceinline__ unsigned short f2bf(float f) {
  unsigned u = __float_as_uint(f);
  unsigned r = u + 0x7fffu + ((u >> 16) & 1u);   // RNE
  return (unsigned short)(r >> 16);
}
__device__ __forceinline__ float bf2f(unsigned short u) {
  return __uint_as_float(((unsigned)u) << 16);
}

// global -> LDS async DMA, 16 B per lane; LDS dest is wave-uniform base,
// HW scatters lane i to base + i*16.
__device__ __forceinline__ void async16(const void* g, void* l) {
  __builtin_amdgcn_global_load_lds(
      (const __attribute__((address_space(1))) void*)(unsigned long long)(uintptr_t)g,
      (__attribute__((address_space(3))) void*)(unsigned int)(uintptr_t)l,
      16, 0, 0);
}

// ---------------- K1: routing (blocks 0..31) + x->bf16 convert (32..4127) --
__global__ __launch_bounds__(256) void route_conv_kernel(
    const float* __restrict__ key, const float* __restrict__ aw,
    const float* __restrict__ ab, float* __restrict__ resp,
    const float4* __restrict__ x, ushort4* __restrict__ xb) {
  const int tid = threadIdx.x;
  if (blockIdx.x >= 32) {
    // convert: 4096 blocks x 256 threads x 8 float4 = 8388608 float4
    const int i0 = (blockIdx.x - 32) * 256 + tid;
    #pragma unroll
    for (int j = 0; j < 8; ++j) {
      const int i = i0 + j * 1048576;
      float4 v = x[i];
      ushort4 o;
      o.x = f2bf(v.x); o.y = f2bf(v.y); o.z = f2bf(v.z); o.w = f2bf(v.w);
      xb[i] = o;
    }
    return;
  }
  // routing: one block per batch element
  __shared__ float part[16][17];
  __shared__ float logit[16];
  const int b = blockIdx.x;
  const int e = tid & 15, ks = tid >> 4;          // 16 k-slices of 64
  const float* kb = key + b * 1024 + ks * 64;
  float acc = 0.f;
  #pragma unroll 8
  for (int k = 0; k < 64; ++k)
    acc = fmaf(kb[k], aw[(ks * 64 + k) * 16 + e], acc);
  part[e][ks] = acc;
  __syncthreads();
  if (tid < 16) {
    float s = ab[tid];
    #pragma unroll
    for (int j = 0; j < 16; ++j) s += part[tid][j];
    logit[tid] = s;
  }
  __syncthreads();
  if (tid < 16) {
    float m = logit[0];
    #pragma unroll
    for (int j = 1; j < 16; ++j) m = fmaxf(m, logit[j]);
    float s = 0.f;
    #pragma unroll
    for (int j = 0; j < 16; ++j) s += expf(logit[j] - m);
    resp[b * 16 + tid] = expf(logit[tid] - m) / s;
  }
}

// ---------------- K2: W[b] = sum_e resp[b,e]*pw_w1[e] (bf16) + loss --------
// 1024 blocks x 256 threads, one float4 position each; v[16] held in
// registers (launch_bounds(256,4) -> 128 VGPR cap, ~95 used, no spill).
__global__ __launch_bounds__(256, 4) void mix_loss_kernel(
    const float4* __restrict__ pw, const float* __restrict__ resp,
    ushort4* __restrict__ W, float* __restrict__ loss_out) {
  __shared__ float rs[512];
  const int tid = threadIdx.x;
  rs[tid] = resp[tid];
  rs[tid + 256] = resp[tid + 256];
  __syncthreads();
  if (blockIdx.x == 0 && tid == 0) {
    float imp[16];
    float mu = 0.f;
    #pragma unroll
    for (int e = 0; e < 16; ++e) {
      float s = 0.f;
      for (int bb = 0; bb < 32; ++bb) s += rs[bb * 16 + e];
      imp[e] = s; mu += s;
    }
    mu *= (1.f / 16.f);
    float var = 0.f;
    #pragma unroll
    for (int e = 0; e < 16; ++e) { float d = imp[e] - mu; var += d * d; }
    var *= (1.f / 15.f);                      // ddof=1
    loss_out[0] = 0.01f * sqrtf(var) / mu;
  }
  const int p = blockIdx.x * 256 + tid;        // 262144 vec4 positions
  float4 v[16];
  #pragma unroll
  for (int e = 0; e < 16; ++e) v[e] = pw[e * 262144 + p];
  #pragma unroll
  for (int b = 0; b < 32; ++b) {
    float ax = 0.f, ay = 0.f, az = 0.f, aww = 0.f;
    #pragma unroll
    for (int e = 0; e < 16; ++e) {
      const float r = rs[b * 16 + e];
      ax = fmaf(r, v[e].x, ax); ay = fmaf(r, v[e].y, ay);
      az = fmaf(r, v[e].z, az); aww = fmaf(r, v[e].w, aww);
    }
    ushort4 o;
    o.x = f2bf(ax); o.y = f2bf(ay); o.z = f2bf(az); o.w = f2bf(aww);
    W[(size_t)b * 262144 + p] = o;
  }
}

// ---------------- K3: batched GEMM + residual (UNCHANGED from R3) ----------
// out[t,b,o] = bf2f(xb[t,b,o]) + sum_i xb[t,b,i] * W[b,o,i]
// 256x256 tile, 512 threads = 8 waves (2M x 4N), wave tile 128x64.
// BK=32, 4-buffer LDS ring (128 KB), counted vmcnt(12) gates, raw s_barrier.
__global__ __launch_bounds__(512, 2) void gemm_kernel(
    const unsigned short* __restrict__ xb,   // (T,B,C) bf16
    const unsigned short* __restrict__ Wb,   // (B,C,C) bf16 [b][o][i]
    float* __restrict__ out) {
  __shared__ unsigned short lds[4][2][8192];     // [buf][A/B][256 rows x 32 k]
  const int tid  = threadIdx.x;
  const int lane = tid & 63;
  const int wave = tid >> 6;                     // 0..7
  const int wm = wave >> 2;                      // 0..1 : 128-row half
  const int wn = wave & 3;                       // 0..3 : 64-col quarter

  const int gid   = blockIdx.x;                  // 0..511
  const int xcd   = gid & 7;
  const int local = gid >> 3;                    // 0..63
  const int b     = xcd * 4 + (local >> 4);      // 4 batches per XCD
  const int sub   = local & 15;
  const int t0    = (sub >> 2) * 256;
  const int o0    = (sub & 3) * 256;

  // staging source pointers: per tile each thread loads 2 A + 2 B chunks.
  // chunk s = j*512+tid -> row r = s>>2, slot c = s&3 holds global granule
  // c ^ XSWZ(r) (pre-swizzled source; linear LDS dest; read undoes the XOR).
  const unsigned short* gA[2];
  const unsigned short* gB[2];
  #pragma unroll
  for (int j = 0; j < 2; ++j) {
    const int s  = j * 512 + tid;
    const int r  = s >> 2;
    const int cg = (s & 3) ^ XSWZ(r);
    gA[j] = xb + (size_t)(t0 + r) * 32768 + (size_t)b * 1024 + cg * 8;
    gB[j] = Wb + (size_t)b * 1048576 + (size_t)(o0 + r) * 1024 + cg * 8;
  }

  floatx4 acc[8][4];
  #pragma unroll
  for (int a = 0; a < 8; ++a)
    #pragma unroll
    for (int ni = 0; ni < 4; ++ni)
      acc[a][ni] = floatx4{0.f, 0.f, 0.f, 0.f};

  auto stage = [&](int bufi) {
    #pragma unroll
    for (int j = 0; j < 2; ++j) {
      const int dst = (j * 512 + wave * 64) * 8;   // elems; lane adds +lane*8
      async16(gA[j], &lds[bufi][0][dst]);
      async16(gB[j], &lds[bufi][1][dst]);
      gA[j] += 32; gB[j] += 32;
    }
  };

  auto compute = [&](int bufi) {
    const unsigned short* lA = &lds[bufi][0][0];
    const unsigned short* lB = &lds[bufi][1][0];
    bf16x8 bfr[4];
    #pragma unroll
    for (int ni = 0; ni < 4; ++ni) {
      const int r = wn * 64 + ni * 16 + (lane & 15);
      const int slot = (lane >> 4) ^ XSWZ(r);
      bfr[ni] = *(const bf16x8*)(lB + r * 32 + slot * 8);
    }
    #pragma unroll
    for (int half = 0; half < 2; ++half) {
      bf16x8 afr[4];
      #pragma unroll
      for (int mi = 0; mi < 4; ++mi) {
        const int r = wm * 128 + half * 64 + mi * 16 + (lane & 15);
        const int slot = (lane >> 4) ^ XSWZ(r);
        afr[mi] = *(const bf16x8*)(lA + r * 32 + slot * 8);
      }
      __builtin_amdgcn_s_setprio(1);
      #pragma unroll
      for (int mi = 0; mi < 4; ++mi)
        #pragma unroll
        for (int ni = 0; ni < 4; ++ni)
          acc[half * 4 + mi][ni] = __builtin_amdgcn_mfma_f32_16x16x32_bf16(
              afr[mi], bfr[ni], acc[half * 4 + mi][ni], 0, 0, 0);
      __builtin_amdgcn_s_setprio(0);
      if (half == 0) __builtin_amdgcn_s_barrier();   // phase split (T5 fuel)
    }
  };

  // prologue: fill 3 of 4 ring slots (12 loads in flight / thread)
  stage(0); stage(1); stage(2);

  for (int t = 0; t < 32; ++t) {
    if (t <= 28) {
      stage((t + 3) & 3);        // dest buffer freed by iter t-1's end barrier
      asm volatile("s_waitcnt vmcnt(12)" ::: "memory");   // tile t landed
    } else if (t == 29) {
      asm volatile("s_waitcnt vmcnt(8)" ::: "memory");
    } else if (t == 30) {
      asm volatile("s_waitcnt vmcnt(4)" ::: "memory");
    } else {
      asm volatile("s_waitcnt vmcnt(0)" ::: "memory");
    }
    __builtin_amdgcn_s_barrier();          // tile t globally visible
    asm volatile("" ::: "memory");
    compute(t & 3);
    asm volatile("s_waitcnt lgkmcnt(0)" ::: "memory");  // my LDS reads done
    __builtin_amdgcn_s_barrier();          // buffer t&3 free for reuse
  }

  // epilogue: C/D layout col=lane&15, row=(lane>>4)*4+reg; residual from xb
  #pragma unroll
  for (int a = 0; a < 8; ++a) {
    const int tb = t0 + wm * 128 + (a >> 2) * 64 + (a & 3) * 16 + (lane >> 4) * 4;
    #pragma unroll
    for (int ni = 0; ni < 4; ++ni) {
      const int o = o0 + wn * 64 + ni * 16 + (lane & 15);
      #pragma unroll
      for (int v = 0; v < 4; ++v) {
        const size_t idx = (size_t)(tb + v) * 32768 + (size_t)b * 1024 + o;
        out[idx] = acc[a][ni][v] + bf2f(xb[idx]);
      }
    }
  }
}

extern "C" void kernel_launch(void* const* d_in, const int* in_sizes, int n_in,
                              void* d_out, int out_size, void* d_ws, size_t ws_size,
                              hipStream_t stream) {
  const float* x   = (const float*)d_in[0];   // (1024,32,1024)
  const float* key = (const float*)d_in[1];   // (1,32,1024)
  const float* aw  = (const float*)d_in[2];   // (1024,16)
  const float* ab  = (const float*)d_in[3];   // (16,)
  const float* pw  = (const float*)d_in[4];   // (16, 1048576)
  float* out = (float*)d_out;                 // 33554432 + 1

  char* ws = (char*)d_ws;
  unsigned short* Wb = (unsigned short*)ws;                    // 67108864 B
  unsigned short* xb = (unsigned short*)(ws + 67108864);       // 67108864 B
  float* resp        = (float*)(ws + 134217728);               // 2 KB

  route_conv_kernel<<<4128, 256, 0, stream>>>(key, aw, ab, resp,
                                              (const float4*)x, (ushort4*)xb);
  mix_loss_kernel<<<1024, 256, 0, stream>>>((const float4*)pw, resp,
                                            (ushort4*)Wb, out + TBC);
  gemm_kernel<<<512, 512, 0, stream>>>(xb, Wb, out);
}

// Round 3
// 381.018 us; speedup vs baseline: 1.0761x; 1.0575x over previous
//
#include <hip/hip_runtime.h>
#include <stdint.h>

// Problem: T=1024, B=32, C=1024, K=1024, E=16
//   out0 (T,B,C) fp32 = x + einsum('rboi,tbi->tbo', (resp@pw_w1).reshape(1,B,C,C), x)
//   out1 scalar loss
//
// R5 changes vs R4:
//   - gemm: BK=64 double-buffer (128 KB LDS, [2buf][A/B][2half][128][64]).
//     Per K-tile: 24 ds_read_b128 + 64 MFMA between ONE barrier pair
//     (R4: 12/32 at BK=32 -> 2x barrier amortization). Granule swizzle
//     g ^= (r&7) over full-128B rows: 8 positions, bank-uniform (R4's 4-pos
//     swizzle left 6.3M conflicts). Stage of tile j+2 issued right after the
//     barrier that frees its buffer; gate is counted vmcnt(8) (tile j landed,
//     j+1 stays in flight) -- never vmcnt(0) until the last tile. Fragment
//     loads are plain C++ (compiler emits fine lgkmcnt), setprio(1) around
//     each 32-MFMA cluster.
//   - mix_loss: __launch_bounds__(256,2) -> 256-VGPR cap, v[16] cannot spill.
//   - convert: back to pure-linear addressing (R2's fastest pattern).

#define TBC   (1024*32*1024)   // 33554432

typedef __attribute__((ext_vector_type(8))) __bf16 bf16x8;
typedef __attribute__((ext_vector_type(4))) float  floatx4;

__device__ __forceinline__ unsigned short f2bf(float f) {
  unsigned u = __float_as_uint(f);
  unsigned r = u + 0x7fffu + ((u >> 16) & 1u);   // RNE
  return (unsigned short)(r >> 16);
}
__device__ __forceinline__ float bf2f(unsigned short u) {
  return __uint_as_float(((unsigned)u) << 16);
}

// global -> LDS async DMA, 16 B per lane; LDS dest is wave-uniform base,
// HW scatters lane i to base + i*16.
__device__ __forceinline__ void async16(const void* g, void* l) {
  __builtin_amdgcn_global_load_lds(
      (const __attribute__((address_space(1))) void*)(unsigned long long)(uintptr_t)g,
      (__attribute__((address_space(3))) void*)(unsigned int)(uintptr_t)l,
      16, 0, 0);
}

// ---------------- K1: routing (blocks 0..31) + x->bf16 convert ------------
__global__ __launch_bounds__(256) void route_conv_kernel(
    const float* __restrict__ key, const float* __restrict__ aw,
    const float* __restrict__ ab, float* __restrict__ resp,
    const float4* __restrict__ x, ushort4* __restrict__ xb) {
  const int tid = threadIdx.x;
  if (blockIdx.x >= 32) {
    // convert: 8192 blocks x 256 threads x 4 float4, fully linear
    const int base = (blockIdx.x - 32) * 1024 + tid;
    #pragma unroll
    for (int j = 0; j < 4; ++j) {
      const int i = base + j * 256;
      float4 v = x[i];
      ushort4 o;
      o.x = f2bf(v.x); o.y = f2bf(v.y); o.z = f2bf(v.z); o.w = f2bf(v.w);
      xb[i] = o;
    }
    return;
  }
  // routing: one block per batch element
  __shared__ float part[16][17];
  __shared__ float logit[16];
  const int b = blockIdx.x;
  const int e = tid & 15, ks = tid >> 4;          // 16 k-slices of 64
  const float* kb = key + b * 1024 + ks * 64;
  float acc = 0.f;
  #pragma unroll 8
  for (int k = 0; k < 64; ++k)
    acc = fmaf(kb[k], aw[(ks * 64 + k) * 16 + e], acc);
  part[e][ks] = acc;
  __syncthreads();
  if (tid < 16) {
    float s = ab[tid];
    #pragma unroll
    for (int j = 0; j < 16; ++j) s += part[tid][j];
    logit[tid] = s;
  }
  __syncthreads();
  if (tid < 16) {
    float m = logit[0];
    #pragma unroll
    for (int j = 1; j < 16; ++j) m = fmaxf(m, logit[j]);
    float s = 0.f;
    #pragma unroll
    for (int j = 0; j < 16; ++j) s += expf(logit[j] - m);
    resp[b * 16 + tid] = expf(logit[tid] - m) / s;
  }
}

// ---------------- K2: W[b] = sum_e resp[b,e]*pw_w1[e] (bf16) + loss --------
// 1024 blocks x 256 threads, one float4 position each; launch_bounds(256,2)
// -> 256 VGPR cap, v[16] provably register-resident.
__global__ __launch_bounds__(256, 2) void mix_loss_kernel(
    const float4* __restrict__ pw, const float* __restrict__ resp,
    ushort4* __restrict__ W, float* __restrict__ loss_out) {
  __shared__ float rs[512];
  const int tid = threadIdx.x;
  rs[tid] = resp[tid];
  rs[tid + 256] = resp[tid + 256];
  __syncthreads();
  if (blockIdx.x == 0 && tid == 0) {
    float imp[16];
    float mu = 0.f;
    #pragma unroll
    for (int e = 0; e < 16; ++e) {
      float s = 0.f;
      for (int bb = 0; bb < 32; ++bb) s += rs[bb * 16 + e];
      imp[e] = s; mu += s;
    }
    mu *= (1.f / 16.f);
    float var = 0.f;
    #pragma unroll
    for (int e = 0; e < 16; ++e) { float d = imp[e] - mu; var += d * d; }
    var *= (1.f / 15.f);                      // ddof=1
    loss_out[0] = 0.01f * sqrtf(var) / mu;
  }
  const int p = blockIdx.x * 256 + tid;        // 262144 vec4 positions
  float4 v[16];
  #pragma unroll
  for (int e = 0; e < 16; ++e) v[e] = pw[e * 262144 + p];
  #pragma unroll
  for (int b = 0; b < 32; ++b) {
    float ax = 0.f, ay = 0.f, az = 0.f, aww = 0.f;
    #pragma unroll
    for (int e = 0; e < 16; ++e) {
      const float r = rs[b * 16 + e];
      ax = fmaf(r, v[e].x, ax); ay = fmaf(r, v[e].y, ay);
      az = fmaf(r, v[e].z, az); aww = fmaf(r, v[e].w, aww);
    }
    ushort4 o;
    o.x = f2bf(ax); o.y = f2bf(ay); o.z = f2bf(az); o.w = f2bf(aww);
    W[(size_t)b * 262144 + p] = o;
  }
}

// ---------------- K3: batched GEMM + residual ------------------------------
// out[t,b,o] = bf2f(xb[t,b,o]) + sum_i xb[t,b,i] * W[b,o,i]
// 256x256 tile, 512 threads = 8 waves (2M x 4N), wave tile 128x64, BK=64.
// LDS [2buf][A/B][2half][128 rows][64 k] bf16 = 128 KB, 1 block/CU.
// Swizzle: 16B granule g stored at g ^ (r&7) (row stride 128B = 8 granules,
// bijective, bank-uniform for both DMA writes and frag reads).
__global__ __launch_bounds__(512, 2) void gemm_kernel(
    const unsigned short* __restrict__ xb,   // (T,B,C) bf16
    const unsigned short* __restrict__ Wb,   // (B,C,C) bf16 [b][o][i]
    float* __restrict__ out) {
  __shared__ unsigned short lds[65536];          // 128 KB
  const int tid  = threadIdx.x;
  const int lane = tid & 63;
  const int ln15 = lane & 15;
  const int hi   = lane >> 4;                    // k-chunk 0..3
  const int wave = tid >> 6;                     // 0..7
  const int wm = wave >> 2;                      // 0..1 : 128-row (t) half
  const int wn = wave & 3;                       // 0..3 : 64-col (o) quarter

  const int gid   = blockIdx.x;                  // 0..511
  const int xcd   = gid & 7;
  const int local = gid >> 3;                    // 0..63
  const int b     = xcd * 4 + (local >> 4);      // 4 batches per XCD
  const int sub   = local & 15;
  const int t0    = (sub >> 2) * 256;
  const int o0    = (sub & 3) * 256;

  // staging sources: 8 granule-chunks per thread per K-tile:
  // [AB][half][s], granule id G = tid + 512*s, row r=G>>3, pos g=G&7,
  // source k-granule = g ^ (r&7)  (inverse-swizzled source, linear LDS dest)
  const unsigned short* src[2][2][2];
  #pragma unroll
  for (int h = 0; h < 2; ++h)
    #pragma unroll
    for (int s = 0; s < 2; ++s) {
      const int G  = tid + 512 * s;
      const int r  = G >> 3;
      const int kg = (G & 7) ^ (r & 7);
      src[0][h][s] = xb + (size_t)(t0 + h * 128 + r) * 32768 + (size_t)b * 1024 + kg * 8;
      src[1][h][s] = Wb + (size_t)b * 1048576 + (size_t)(o0 + h * 128 + r) * 1024 + kg * 8;
    }

  floatx4 acc[8][4];
  #pragma unroll
  for (int a = 0; a < 8; ++a)
    #pragma unroll
    for (int ni = 0; ni < 4; ++ni)
      acc[a][ni] = floatx4{0.f, 0.f, 0.f, 0.f};

  auto stage = [&](int bufBase) {                // 8 x async16 per thread
    #pragma unroll
    for (int ab = 0; ab < 2; ++ab)
      #pragma unroll
      for (int h = 0; h < 2; ++h)
        #pragma unroll
        for (int s = 0; s < 2; ++s) {
          async16(src[ab][h][s],
                  lds + bufBase + ab * 16384 + h * 8192 + (wave * 64 + 512 * s) * 8);
          src[ab][h][s] += 64;                   // next K-tile
        }
  };

  auto compute = [&](int bufBase) {
    const unsigned short* LA = lds + bufBase + wm * 8192;
    const unsigned short* LB = lds + bufBase + 16384 + (wn >> 1) * 8192;
    bf16x8 Bf[4][2];
    #pragma unroll
    for (int ni = 0; ni < 4; ++ni) {
      const int r = (wn & 1) * 64 + ni * 16 + ln15;
      #pragma unroll
      for (int kk = 0; kk < 2; ++kk)
        Bf[ni][kk] = *(const bf16x8*)(LB + r * 64 + (((kk * 4 + hi) ^ (r & 7)) * 8));
    }
    #pragma unroll
    for (int qm = 0; qm < 2; ++qm) {
      bf16x8 Af[4][2];
      #pragma unroll
      for (int mi = 0; mi < 4; ++mi) {
        const int r = (qm * 4 + mi) * 16 + ln15;
        #pragma unroll
        for (int kk = 0; kk < 2; ++kk)
          Af[mi][kk] = *(const bf16x8*)(LA + r * 64 + (((kk * 4 + hi) ^ (r & 7)) * 8));
      }
      __builtin_amdgcn_s_setprio(1);
      #pragma unroll
      for (int mi = 0; mi < 4; ++mi)
        #pragma unroll
        for (int ni = 0; ni < 4; ++ni)
          #pragma unroll
          for (int kk = 0; kk < 2; ++kk)
            acc[qm * 4 + mi][ni] = __builtin_amdgcn_mfma_f32_16x16x32_bf16(
                Af[mi][kk], Bf[ni][kk], acc[qm * 4 + mi][ni], 0, 0, 0);
      __builtin_amdgcn_s_setprio(0);
    }
  };

  // prologue: tiles 0,1 into bufs 0,1 (16 loads in flight / thread)
  stage(0);
  stage(32768);

  for (int j = 0; j < 16; ++j) {
    // gate: tile j's 8 loads landed (tile j+1's 8 stay in flight)
    if (j < 15) asm volatile("s_waitcnt vmcnt(8)" ::: "memory");
    else        asm volatile("s_waitcnt vmcnt(0)" ::: "memory");
    __builtin_amdgcn_s_barrier();                // collective: tile j visible
    compute((j & 1) * 32768);
    __builtin_amdgcn_s_barrier();                // all reads of buf j&1 done
    asm volatile("" ::: "memory");
    if (j < 14) stage((j & 1) * 32768);          // tile j+2 -> freed buffer
  }

  // epilogue: C/D layout col=lane&15, row=(lane>>4)*4+reg; residual from xb
  #pragma unroll
  for (int mi = 0; mi < 8; ++mi) {
    const int tb = t0 + wm * 128 + mi * 16 + hi * 4;
    #pragma unroll
    for (int ni = 0; ni < 4; ++ni) {
      const int o = o0 + wn * 64 + ni * 16 + ln15;
      #pragma unroll
      for (int v = 0; v < 4; ++v) {
        const size_t idx = (size_t)(tb + v) * 32768 + (size_t)b * 1024 + o;
        out[idx] = acc[mi][ni][v] + bf2f(xb[idx]);
      }
    }
  }
}

extern "C" void kernel_launch(void* const* d_in, const int* in_sizes, int n_in,
                              void* d_out, int out_size, void* d_ws, size_t ws_size,
                              hipStream_t stream) {
  const float* x   = (const float*)d_in[0];   // (1024,32,1024)
  const float* key = (const float*)d_in[1];   // (1,32,1024)
  const float* aw  = (const float*)d_in[2];   // (1024,16)
  const float* ab  = (const float*)d_in[3];   // (16,)
  const float* pw  = (const float*)d_in[4];   // (16, 1048576)
  float* out = (float*)d_out;                 // 33554432 + 1

  char* ws = (char*)d_ws;
  unsigned short* Wb = (unsigned short*)ws;                    // 67108864 B
  unsigned short* xb = (unsigned short*)(ws + 67108864);       // 67108864 B
  float* resp        = (float*)(ws + 134217728);               // 2 KB

  route_conv_kernel<<<8224, 256, 0, stream>>>(key, aw, ab, resp,
                                              (const float4*)x, (ushort4*)xb);
  mix_loss_kernel<<<1024, 256, 0, stream>>>((const float4*)pw, resp,
                                            (ushort4*)Wb, out + TBC);
  gemm_kernel<<<512, 512, 0, stream>>>(xb, Wb, out);
}